// Round 2
// baseline (605.645 us; speedup 1.0000x reference)
//
#include <hip/hip_runtime.h>
#include <hip/hip_bf16.h>
#include <math.h>
#include <stdint.h>

// Problem constants
#define E_DIM 1024
#define D_DIM 64
#define H_DIM 16
#define B_SZ  8
#define L_SEQ 4096
#define M_TOK (B_SZ * L_SEQ)   // 32768 tokens
#define NCAT  2112              // 1024 (a) + 1024 (b) + 64 (dx)
#define NPAD  2304              // padded to 9 tiles of 256
#define CHUNK 64                // scan chunk
#define NCHUNK (L_SEQ / CHUNK)  // 64

typedef float  f32x4  __attribute__((ext_vector_type(4)));
typedef __bf16 bf16x8 __attribute__((ext_vector_type(8)));
typedef __bf16 bf16x4 __attribute__((ext_vector_type(4)));

__device__ __forceinline__ float tanh_fast(float v) {
  float vc = fminf(fmaxf(v, -12.f), 12.f);
  float ex = __expf(vc + vc);
  return (ex - 1.f) / (ex + 1.f);
}
__device__ __forceinline__ void load_lds16(const void* g, void* l) {
  __builtin_amdgcn_global_load_lds(
      (const __attribute__((address_space(1))) void*)g,
      (__attribute__((address_space(3))) void*)l, 16, 0, 0);
}

// ---------------------------------------------------------------- cast emb f32 -> bf16
__global__ __launch_bounds__(256) void cast_emb(const float* __restrict__ in,
                                                bf16x4* __restrict__ out) {
  int i = blockIdx.x * 256 + threadIdx.x;      // exactly M_TOK*E/4 threads
  float4 v = ((const float4*)in)[i];
  bf16x4 o;
  o[0] = (__bf16)v.x; o[1] = (__bf16)v.y; o[2] = (__bf16)v.z; o[3] = (__bf16)v.w;
  out[i] = o;
}

// ---------------------------------------------------------------- pack Wa|Wb|Wd -> W^T [NPAD][E] bf16 + bias
__global__ __launch_bounds__(256) void pack_w(
    const float* __restrict__ Wa, const float* __restrict__ ba,
    const float* __restrict__ Wb, const float* __restrict__ bb,
    const float* __restrict__ Wd, const float* __restrict__ bd,
    __bf16* __restrict__ wcat, float* __restrict__ bias) {
  int gid = blockIdx.x * 256 + threadIdx.x;    // exactly NPAD*E threads
  int n = gid >> 10, k = gid & 1023;
  float w, bv;
  if (n < 1024) {        // a-gate: Wa[h,e,d], col n = h*64+d
    int h = n >> 6, d = n & 63;
    w = Wa[((h << 10) | k) * 64 + d]; bv = ba[n];
  } else if (n < 2048) { // b-gate
    int nn = n - 1024; int h = nn >> 6, d = nn & 63;
    w = Wb[((h << 10) | k) * 64 + d]; bv = bb[nn];
  } else if (n < NCAT) { // dx: Wd[e,d]
    int d = n - 2048;
    w = Wd[k * 64 + d];  bv = bd[d];
  } else { w = 0.f; bv = 0.f; }  // pad
  wcat[n * 1024 + k] = (__bf16)w;
  if (k == 0) bias[n] = bv;
}

// ---------------------------------------------------------------- pack FFN weights -> bf16 LDS-image layouts
__global__ __launch_bounds__(256) void pack_ffnw(
    const float* __restrict__ W1, const float* __restrict__ W2,
    const float* __restrict__ Wp,
    __bf16* __restrict__ g_w1t, __bf16* __restrict__ g_w2t,
    __bf16* __restrict__ g_wpt) {
  int idx = blockIdx.x * 256 + threadIdx.x;    // 36864 threads
  if (idx < 16384) {
    int k = idx >> 8, n = idx & 255;
    g_w1t[n * 72 + k] = (__bf16)W1[idx];
  } else if (idx < 32768) {
    int j = idx - 16384; int k = j >> 6, n = j & 63;
    g_w2t[n * 256 + (((k >> 3) ^ (n & 7)) << 3) + (k & 7)] = (__bf16)W2[j];
  } else {
    int j = idx - 32768; int k = j >> 6, n = j & 63;
    g_wpt[n * 72 + k] = (__bf16)Wp[j];
  }
}

// ---------------------------------------------------------------- pack Wc -> WcT[h][e][d] bf16 (B^T layout for MFMA)
__global__ __launch_bounds__(256) void pack_wct(const float* __restrict__ Wc,
                                                __bf16* __restrict__ wct) {
  int idx = blockIdx.x * 256 + threadIdx.x;    // 65536 threads
  int h = idx >> 12, e = (idx >> 6) & 63, d = idx & 63;
  wct[idx] = (__bf16)Wc[h * 4096 + d * 64 + e];
}

// ---------------------------------------------------------------- bf16 MFMA GEMM, 256x256 tile, BK=64.
// Faithful 8-phase-style cadence: per K-tile 4 phases, each phase =
// {ds_read frags; stage 1 half-tile; barrier; lgkmcnt(0); 16 MFMA; barrier}.
// Counted vmcnt(4) once per K-tile (never 0 until the tail drain).
// LDS = 2 dbuf x 2 half x [128][64] x (A,B) = 128 KiB, XOR chunk swizzle.
// 8 waves: wr = w>>2 (M, 2x128), wc = w&3 (N, 4x64). Per-wave out 128x64.
__global__ __launch_bounds__(512, 2) void gemm_fused(
    const __bf16* __restrict__ A, const __bf16* __restrict__ Wt,
    const float* __restrict__ bias,
    __bf16* __restrict__ abuf, __bf16* __restrict__ bbuf, float* __restrict__ dxbuf) {
  __shared__ __bf16 lds[65536];               // A granules [4][128][64] | B granules [4][128][64]
  // bijective XCD swizzle: 1152 blocks = 8 * 144
  const int id = blockIdx.x;
  const int wg = (id & 7) * 144 + (id >> 3);
  const int mt = wg / 9, nt = wg % 9;
  const int m0 = mt * 256, n0 = nt * 256;
  const int t = threadIdx.x;
  const int w = t >> 6, l = t & 63;
  const int wr = w >> 2, wc = w & 3;
  const int q = l >> 4, c16 = l & 15;
  const int cxor = c16 & 7;                   // read-side swizzle term
  const int schk = (l & 7) ^ ((l >> 3) & 7);  // staging: pre-swizzled source chunk

  f32x4 acc[8][4];
#pragma unroll
  for (int i = 0; i < 8; ++i)
#pragma unroll
    for (int j = 0; j < 4; ++j) acc[i][j] = (f32x4)(0.f);

  // stage half-granule: kt = K-tile, isB, h = row-half. [128 rows][64 k] = 16 KB.
  // LDS dest linear (wave-uniform base + lane*16); global source pre-swizzled.
  auto stage = [&](int kt, int isB, int h) {
    const __bf16* src = isB ? Wt : A;
    const int base0 = (isB ? n0 : m0) + h * 128 + w * 16;
    __bf16* dst = lds + (isB ? 32768 : 0) + (((kt & 1) << 1) + h) * 8192 + w * 1024;
#pragma unroll
    for (int r = 0; r < 2; ++r)
      load_lds16(src + (size_t)(base0 + r * 8 + (l >> 3)) * 1024 + kt * 64 + schk * 8,
                 dst + r * 512);
  };

  auto ldA = [&](int d, int i, int ks) -> bf16x8 {
    return *(const bf16x8*)(lds + ((d << 1) + wr) * 8192 + (i * 16 + c16) * 64 +
                            (((ks << 2) + q) ^ cxor) * 8);
  };
  auto ldB = [&](int d, int j, int ks) -> bf16x8 {
    return *(const bf16x8*)(lds + 32768 + ((d << 1) + (wc >> 1)) * 8192 +
                            ((wc & 1) * 64 + j * 16 + c16) * 64 +
                            (((ks << 2) + q) ^ cxor) * 8);
  };

  bf16x8 bfr[4][2];                           // B frags held across the 4 phases of a tile

  // phase: reads + stage issue | barrier, lgkm(0) | 16 MFMA | [vmcnt] barrier
  auto phase = [&](int d, int i0, bool loadB, bool do_stage, int skt, int sisB,
                   int sh, int wait) {
    if (loadB) {
#pragma unroll
      for (int j = 0; j < 4; ++j) {
        bfr[j][0] = ldB(d, j, 0);
        bfr[j][1] = ldB(d, j, 1);
      }
    }
    bf16x8 a00 = ldA(d, i0, 0), a01 = ldA(d, i0, 1);
    bf16x8 a10 = ldA(d, i0 + 1, 0), a11 = ldA(d, i0 + 1, 1);
    if (do_stage) stage(skt, sisB, sh);
    __builtin_amdgcn_sched_barrier(0);
    __builtin_amdgcn_s_barrier();
    asm volatile("s_waitcnt lgkmcnt(0)" ::: "memory");
    __builtin_amdgcn_sched_barrier(0);
    __builtin_amdgcn_s_setprio(1);
#pragma unroll
    for (int ks = 0; ks < 2; ++ks) {
      const bf16x8 a0 = ks ? a01 : a00;
      const bf16x8 a1 = ks ? a11 : a10;
#pragma unroll
      for (int j = 0; j < 4; ++j)
        acc[i0][j] = __builtin_amdgcn_mfma_f32_16x16x32_bf16(a0, bfr[j][ks], acc[i0][j], 0, 0, 0);
#pragma unroll
      for (int j = 0; j < 4; ++j)
        acc[i0 + 1][j] = __builtin_amdgcn_mfma_f32_16x16x32_bf16(a1, bfr[j][ks], acc[i0 + 1][j], 0, 0, 0);
    }
    __builtin_amdgcn_s_setprio(0);
    __builtin_amdgcn_sched_barrier(0);
    if (wait == 0)      asm volatile("s_waitcnt vmcnt(0)" ::: "memory");
    else if (wait == 4) asm volatile("s_waitcnt vmcnt(4)" ::: "memory");
    __builtin_amdgcn_s_barrier();
  };

  // prologue: tile 0 fully + B of tile 1 in flight
  stage(0, 0, 0); stage(0, 0, 1); stage(0, 1, 0); stage(0, 1, 1);
  stage(1, 1, 0); stage(1, 1, 1);
  asm volatile("s_waitcnt vmcnt(4)" ::: "memory");  // tile 0 resident, B(1) in flight
  __builtin_amdgcn_s_barrier();

#pragma unroll 2
  for (int tt = 0; tt < 16; ++tt) {
    const int d = tt & 1;
    const bool s1 = (tt + 1) < 16, s2 = (tt + 2) < 16;
    phase(d, 0, true,  s1, tt + 1, 0, 0, -1);
    phase(d, 2, false, s1, tt + 1, 0, 1, -1);
    phase(d, 4, false, s2, tt + 2, 1, 0, -1);
    phase(d, 6, false, s2, tt + 2, 1, 1, (tt < 14) ? 4 : (tt == 14 ? 0 : -1));
  }

  // epilogue: C/D layout col=lane&15 (N), row=(lane>>4)*4+reg (M)
#pragma unroll
  for (int j = 0; j < 4; ++j) {
    int n = n0 + wc * 64 + j * 16 + c16;
    if (n >= NCAT) continue;                 // pad columns (wave-uniform per j)
    float bv = bias[n];
#pragma unroll
    for (int i = 0; i < 8; ++i) {
      int mbase = m0 + wr * 128 + i * 16 + q * 4;
#pragma unroll
      for (int r = 0; r < 4; ++r) {
        float v = acc[i][j][r] + bv;
        int m = mbase + r;
        if (n < 1024)            abuf[(size_t)m * 1024 + n] = (__bf16)tanh_fast(v);
        else if (n < 2048)       bbuf[(size_t)m * 1024 + (n - 1024)] = (__bf16)v;
        else                     dxbuf[m * 64 + (n - 2048)] = v;
      }
    }
  }
}

// ---------------------------------------------------------------- scan phase 1: chunk-local, bf16 I/O, f32 math
// in-place: abuf <- cumprod(a), bbuf <- local h; per-chunk A,hlast out (f32).
__global__ __launch_bounds__(256) void scan_local_bf(
    __bf16* __restrict__ abuf, __bf16* __restrict__ bbuf,
    float* __restrict__ cA, float* __restrict__ cH) {
  int bc = blockIdx.x;                          // chunk id (m-major), 512 blocks
  int n4 = threadIdx.x * 4;                     // 4 columns per thread
  size_t base = (size_t)bc * CHUNK * 1024 + n4;
  float p[4] = {1.f, 1.f, 1.f, 1.f}, h[4] = {0.f, 0.f, 0.f, 0.f};
#pragma unroll 4
  for (int s = 0; s < CHUNK; ++s) {
    size_t idx = base + (size_t)s * 1024;
    bf16x4 av = *(const bf16x4*)(abuf + idx);
    bf16x4 bv = *(const bf16x4*)(bbuf + idx);
    bf16x4 po, ho;
#pragma unroll
    for (int i = 0; i < 4; ++i) {
      float a = (float)av[i];
      p[i] *= a;
      h[i] = fmaf(a, h[i], (float)bv[i]);
      po[i] = (__bf16)p[i];
      ho[i] = (__bf16)h[i];
    }
    *(bf16x4*)(abuf + idx) = po;
    *(bf16x4*)(bbuf + idx) = ho;
  }
  int ci = bc * 1024 + n4;                      // bc = b*NCHUNK + c (m-major)
  float4 pv = {p[0], p[1], p[2], p[3]};
  float4 hv = {h[0], h[1], h[2], h[3]};
  *(float4*)(cA + ci) = pv;
  *(float4*)(cH + ci) = hv;
}

// ---------------------------------------------------------------- scan phase 2: carries over chunks (f32)
__global__ __launch_bounds__(256) void scan_carry(
    const float* __restrict__ cA, const float* __restrict__ cH, float* __restrict__ cIn) {
  int gid = blockIdx.x * 256 + threadIdx.x;    // 8192 threads: (b, n)
  int n = gid & 1023, b = gid >> 10;
  float carry = 0.f;
  for (int c = 0; c < NCHUNK; ++c) {
    int idx = (b * NCHUNK + c) * 1024 + n;
    cIn[idx] = carry;                           // exclusive carry into chunk c
    carry = fmaf(cA[idx], carry, cH[idx]);
  }
}

// ---------------------------------------------------------------- heads via MFMA
// 64 tokens/block (= exactly one scan chunk), 4 waves x 16 tokens each; all 16 heads per wave.
__global__ __launch_bounds__(256) void heads_mfma(
    const __bf16* __restrict__ ahat, const __bf16* __restrict__ hloc,
    const float* __restrict__ dxbuf, const float* __restrict__ cIn,
    const __bf16* __restrict__ wct, const float* __restrict__ bch,
    const float* __restrict__ head_w, const float* __restrict__ hng,
    const float* __restrict__ hnb, const float* __restrict__ ng,
    const float* __restrict__ nbv, float* __restrict__ ubuf) {
  __shared__ float carryS[1024];
  const int tid = threadIdx.x, w = tid >> 6, l = tid & 63;
  const int q = l >> 4, c16 = l & 15;
  const int m0 = blockIdx.x * 64;
  const int b = m0 >> 12, c = (m0 & 4095) >> 6;  // chunk of 64 tokens
  const int cb = (b * NCHUNK + c) * 1024;
  ((float4*)carryS)[tid] = ((const float4*)(cIn + cb))[tid];
  __syncthreads();

  const size_t arow = (size_t)(m0 + w * 16 + c16) * 1024;  // A-frag token row

  // dx regs in C layout: token q*4+r, e = j*16+c16
  float dxr[4][4];
#pragma unroll
  for (int j = 0; j < 4; ++j)
#pragma unroll
    for (int r = 0; r < 4; ++r)
      dxr[j][r] = dxbuf[(m0 + w * 16 + q * 4 + r) * 64 + j * 16 + c16];

  f32x4 accum[4];
#pragma unroll
  for (int j = 0; j < 4; ++j) accum[j] = (f32x4)(0.f);

  for (int h = 0; h < H_DIM; ++h) {
    // A fragments: reconstruct h_t = cumprod*carry + local (f32), cast bf16
    bf16x8 af[2];
#pragma unroll
    for (int ks = 0; ks < 2; ++ks) {
      int dbase = h * 64 + ks * 32 + q * 8;
      bf16x8 av = *(const bf16x8*)(ahat + arow + dbase);
      bf16x8 hv = *(const bf16x8*)(hloc + arow + dbase);
      float4 cv0 = *(const float4*)(carryS + dbase);
      float4 cv1 = *(const float4*)(carryS + dbase + 4);
      bf16x8 hf;
      hf[0] = (__bf16)fmaf((float)av[0], cv0.x, (float)hv[0]);
      hf[1] = (__bf16)fmaf((float)av[1], cv0.y, (float)hv[1]);
      hf[2] = (__bf16)fmaf((float)av[2], cv0.z, (float)hv[2]);
      hf[3] = (__bf16)fmaf((float)av[3], cv0.w, (float)hv[3]);
      hf[4] = (__bf16)fmaf((float)av[4], cv1.x, (float)hv[4]);
      hf[5] = (__bf16)fmaf((float)av[5], cv1.y, (float)hv[5]);
      hf[6] = (__bf16)fmaf((float)av[6], cv1.z, (float)hv[6]);
      hf[7] = (__bf16)fmaf((float)av[7], cv1.w, (float)hv[7]);
      af[ks] = hf;
    }
    // GEMM: [16 tokens x 64d] @ WcT[h] -> [16 x 64e]
    f32x4 acc[4];
#pragma unroll
    for (int j = 0; j < 4; ++j) acc[j] = (f32x4)(0.f);
#pragma unroll
    for (int ks = 0; ks < 2; ++ks)
#pragma unroll
      for (int j = 0; j < 4; ++j) {
        bf16x8 bf = *(const bf16x8*)(wct + h * 4096 + (j * 16 + c16) * 64 + ks * 32 + q * 8);
        acc[j] = __builtin_amdgcn_mfma_f32_16x16x32_bf16(af[ks], bf, acc[j], 0, 0, 0);
      }
    // bias + dx, per-head LN over e, weighted accumulate
    float hw = head_w[h];
    float g4[4], be4[4], bb4[4];
#pragma unroll
    for (int j = 0; j < 4; ++j) {
      int nh = h * 64 + j * 16 + c16;
      g4[j] = hng[nh]; bb4[j] = hnb[nh]; be4[j] = bch[nh];
    }
#pragma unroll
    for (int r = 0; r < 4; ++r) {
      float v0 = acc[0][r] + be4[0] + dxr[0][r];
      float v1 = acc[1][r] + be4[1] + dxr[1][r];
      float v2 = acc[2][r] + be4[2] + dxr[2][r];
      float v3 = acc[3][r] + be4[3] + dxr[3][r];
      float s  = (v0 + v1) + (v2 + v3);
      float s2 = fmaf(v0, v0, fmaf(v1, v1, fmaf(v2, v2, v3 * v3)));
#pragma unroll
      for (int off = 1; off < 16; off <<= 1) {
        s  += __shfl_xor(s, off, 64);
        s2 += __shfl_xor(s2, off, 64);
      }
      float mean = s * (1.f / 64.f);
      float var  = fmaf(s2, 1.f / 64.f, -mean * mean);
      float inv  = rsqrtf(fmaxf(var, 0.f) + 1e-5f);
      accum[0][r] = fmaf(hw, fmaf((v0 - mean) * inv, g4[0], bb4[0]), accum[0][r]);
      accum[1][r] = fmaf(hw, fmaf((v1 - mean) * inv, g4[1], bb4[1]), accum[1][r]);
      accum[2][r] = fmaf(hw, fmaf((v2 - mean) * inv, g4[2], bb4[2]), accum[2][r]);
      accum[3][r] = fmaf(hw, fmaf((v3 - mean) * inv, g4[3], bb4[3]), accum[3][r]);
    }
  }
  // z = (dx + accum)/16; u = z + LN(z)
  float ng4[4], nb4[4];
#pragma unroll
  for (int j = 0; j < 4; ++j) { ng4[j] = ng[j * 16 + c16]; nb4[j] = nbv[j * 16 + c16]; }
#pragma unroll
  for (int r = 0; r < 4; ++r) {
    float z0 = (dxr[0][r] + accum[0][r]) * (1.f / 16.f);
    float z1 = (dxr[1][r] + accum[1][r]) * (1.f / 16.f);
    float z2 = (dxr[2][r] + accum[2][r]) * (1.f / 16.f);
    float z3 = (dxr[3][r] + accum[3][r]) * (1.f / 16.f);
    float s  = (z0 + z1) + (z2 + z3);
    float s2 = fmaf(z0, z0, fmaf(z1, z1, fmaf(z2, z2, z3 * z3)));
#pragma unroll
    for (int off = 1; off < 16; off <<= 1) {
      s  += __shfl_xor(s, off, 64);
      s2 += __shfl_xor(s2, off, 64);
    }
    float mean = s * (1.f / 64.f);
    float var  = fmaf(s2, 1.f / 64.f, -mean * mean);
    float inv  = rsqrtf(fmaxf(var, 0.f) + 1e-5f);
    int mrow = (m0 + w * 16 + q * 4 + r) * 64;
    ubuf[mrow + 0 * 16 + c16] = z0 + fmaf((z0 - mean) * inv, ng4[0], nb4[0]);
    ubuf[mrow + 1 * 16 + c16] = z1 + fmaf((z1 - mean) * inv, ng4[1], nb4[1]);
    ubuf[mrow + 2 * 16 + c16] = z2 + fmaf((z2 - mean) * inv, ng4[2], nb4[2]);
    ubuf[mrow + 3 * 16 + c16] = z3 + fmaf((z3 - mean) * inv, ng4[3], nb4[3]);
  }
}

// ---------------------------------------------------------------- FFN via MFMA: 64-token tile, fused 3 GEMMs
__global__ __launch_bounds__(256) void ffn_mfma(
    const float* __restrict__ ubuf,
    const __bf16* __restrict__ g_w1t, const __bf16* __restrict__ g_w2t,
    const __bf16* __restrict__ g_wpt,
    const float* __restrict__ b1, const float* __restrict__ b2,
    const float* __restrict__ bp, float* __restrict__ out) {
  __shared__ __bf16 pool[32768];               // 65536 B
  const int tid = threadIdx.x, w = tid >> 6, l = tid & 63;
  const int q = l >> 4, c16 = l & 15;
  const int m0 = blockIdx.x * 64;
  __bf16* Us  = pool;            // stride 72
  __bf16* W1T = pool + 4608;     // stride 72
  __bf16* T1S = pool;            // stride 256, chunk-swizzled
  __bf16* W2T = pool + 16384;    // stride 256, chunk-swizzled
  __bf16* HoS = pool;            // stride 72
  __bf16* WpT = pool + 4608;     // stride 72

#pragma unroll
  for (int r = 0; r < 16; ++r) {
    int idx = r * 256 + tid, m = idx >> 6, e = idx & 63;
    Us[m * 72 + e] = (__bf16)ubuf[(size_t)(m0 + m) * 64 + e];
  }
#pragma unroll
  for (int r = 0; r < 9; ++r)    // 2304 16B chunks = 36864 B
    load_lds16(g_w1t + (size_t)(r * 256 + tid) * 8,
               (char*)pool + 9216 + (r * 256 + w * 64) * 16);
  __syncthreads();

  f32x4 acc1[16];
#pragma unroll
  for (int j = 0; j < 16; ++j) acc1[j] = (f32x4)(0.f);
#pragma unroll
  for (int ks = 0; ks < 2; ++ks) {
    bf16x8 a = *(const bf16x8*)(Us + (w * 16 + c16) * 72 + ks * 32 + q * 8);
#pragma unroll
    for (int j = 0; j < 16; ++j) {
      bf16x8 b = *(const bf16x8*)(W1T + (j * 16 + c16) * 72 + ks * 32 + q * 8);
      acc1[j] = __builtin_amdgcn_mfma_f32_16x16x32_bf16(a, b, acc1[j], 0, 0, 0);
    }
  }
  __syncthreads();

#pragma unroll
  for (int r = 0; r < 8; ++r)    // 2048 chunks = 32768 B
    load_lds16(g_w2t + (size_t)(r * 256 + tid) * 8,
               (char*)pool + 32768 + (r * 256 + w * 64) * 16);
#pragma unroll
  for (int j = 0; j < 16; ++j) {
    int n = j * 16 + c16;
    float bv = b1[n];
#pragma unroll
    for (int rr = 0; rr < 4; ++rr) {
      int m = w * 16 + q * 4 + rr;
      float x = acc1[j][rr] + bv;
      float g = 0.5f * x * (1.f + erff(x * 0.70710678118654752f));
      T1S[m * 256 + (((n >> 3) ^ (m & 7)) << 3) + (n & 7)] = (__bf16)g;
    }
  }
  __syncthreads();

  f32x4 acc2[4];
#pragma unroll
  for (int j = 0; j < 4; ++j) acc2[j] = (f32x4)(0.f);
  const int arow2 = w * 16 + c16;
#pragma unroll
  for (int ks = 0; ks < 8; ++ks) {
    bf16x8 a = *(const bf16x8*)(T1S + arow2 * 256 + (((ks * 4 + q) ^ (arow2 & 7)) << 3));
#pragma unroll
    for (int j = 0; j < 4; ++j) {
      int brow = j * 16 + c16;
      bf16x8 b = *(const bf16x8*)(W2T + brow * 256 + (((ks * 4 + q) ^ (brow & 7)) << 3));
      acc2[j] = __builtin_amdgcn_mfma_f32_16x16x32_bf16(a, b, acc2[j], 0, 0, 0);
    }
  }
  __syncthreads();

#pragma unroll
  for (int r = 0; r < 2; ++r)    // 512 of 576 chunks
    load_lds16(g_wpt + (size_t)(r * 256 + tid) * 8,
               (char*)pool + 9216 + (r * 256 + w * 64) * 16);
  if (tid < 64)                  // last 64 chunks, wave 0
    load_lds16(g_wpt + (size_t)(512 + tid) * 8, (char*)pool + 9216 + 512 * 16);
#pragma unroll
  for (int j = 0; j < 4; ++j) {
    int e = j * 16 + c16;
    float bv = b2[e];
#pragma unroll
    for (int rr = 0; rr < 4; ++rr) {
      int m = w * 16 + q * 4 + rr;
      float hres = acc2[j][rr] + bv + ubuf[(size_t)(m0 + m) * 64 + e];
      HoS[m * 72 + e] = (__bf16)hres;
    }
  }
  __syncthreads();

  f32x4 acc3[4];
#pragma unroll
  for (int j = 0; j < 4; ++j) acc3[j] = (f32x4)(0.f);
#pragma unroll
  for (int ks = 0; ks < 2; ++ks) {
    bf16x8 a = *(const bf16x8*)(HoS + (w * 16 + c16) * 72 + ks * 32 + q * 8);
#pragma unroll
    for (int j = 0; j < 4; ++j) {
      bf16x8 b = *(const bf16x8*)(WpT + (j * 16 + c16) * 72 + ks * 32 + q * 8);
      acc3[j] = __builtin_amdgcn_mfma_f32_16x16x32_bf16(a, b, acc3[j], 0, 0, 0);
    }
  }
#pragma unroll
  for (int j = 0; j < 4; ++j) {
    int e = j * 16 + c16;
    float bv = bp[e];
#pragma unroll
    for (int rr = 0; rr < 4; ++rr) {
      int m = w * 16 + q * 4 + rr;
      out[(size_t)(m0 + m) * 64 + e] = acc3[j][rr] + bv;
    }
  }
}

// ----------------------------------------------------------------
extern "C" void kernel_launch(void* const* d_in, const int* in_sizes, int n_in,
                              void* d_out, int out_size, void* d_ws, size_t ws_size,
                              hipStream_t stream) {
  const float* emb    = (const float*)d_in[0];
  const float* Wa     = (const float*)d_in[1];
  const float* ba     = (const float*)d_in[2];
  const float* Wb     = (const float*)d_in[3];
  const float* bb     = (const float*)d_in[4];
  const float* Wc     = (const float*)d_in[5];
  const float* bc     = (const float*)d_in[6];
  const float* head_w = (const float*)d_in[7];
  const float* hn_g   = (const float*)d_in[8];
  const float* hn_b   = (const float*)d_in[9];
  const float* Wd     = (const float*)d_in[10];
  const float* bd     = (const float*)d_in[11];
  const float* W1     = (const float*)d_in[12];
  const float* b1     = (const float*)d_in[13];
  const float* W2     = (const float*)d_in[14];
  const float* b2     = (const float*)d_in[15];
  const float* Wp     = (const float*)d_in[16];
  const float* bp     = (const float*)d_in[17];
  const float* ng     = (const float*)d_in[18];
  const float* nb     = (const float*)d_in[19];
  float* out = (float*)d_out;

  char* wsp = (char*)d_ws;
  size_t off = 0;
  auto alloc = [&](size_t bytes) -> char* {
    char* p = wsp + off;
    off += (bytes + 255) & ~(size_t)255;
    return p;
  };
  __bf16* embh  = (__bf16*)alloc((size_t)M_TOK * E_DIM * 2);   //  67 MB
  __bf16* wcat  = (__bf16*)alloc((size_t)NPAD * E_DIM * 2);    // 4.7 MB
  float*  bias  = (float*)alloc((size_t)NPAD * 4);
  __bf16* abuf  = (__bf16*)alloc((size_t)M_TOK * 1024 * 2);    // 67 MB
  __bf16* bbuf  = (__bf16*)alloc((size_t)M_TOK * 1024 * 2);    // 67 MB
  float*  dxbuf = (float*)alloc((size_t)M_TOK * 64 * 4);       // 8.4 MB
  float*  cA    = (float*)alloc((size_t)512 * 1024 * 4);
  float*  cH    = (float*)alloc((size_t)512 * 1024 * 4);
  float*  cIn   = (float*)alloc((size_t)512 * 1024 * 4);
  float*  ubuf  = (float*)alloc((size_t)M_TOK * 64 * 4);       // 8.4 MB
  __bf16* g_w1t = (__bf16*)alloc((size_t)256 * 72 * 2);
  __bf16* g_w2t = (__bf16*)alloc((size_t)64 * 256 * 2);
  __bf16* g_wpt = (__bf16*)alloc((size_t)64 * 72 * 2);
  __bf16* wct   = (__bf16*)alloc((size_t)H_DIM * 64 * 64 * 2); // 128 KB

  cast_emb<<<dim3(32768), dim3(256), 0, stream>>>(emb, (bf16x4*)embh);
  pack_w<<<dim3(9216), dim3(256), 0, stream>>>(Wa, ba, Wb, bb, Wd, bd, wcat, bias);
  pack_ffnw<<<dim3(144), dim3(256), 0, stream>>>(W1, W2, Wp, g_w1t, g_w2t, g_wpt);
  pack_wct<<<dim3(256), dim3(256), 0, stream>>>(Wc, wct);
  gemm_fused<<<dim3(1152), dim3(512), 0, stream>>>(embh, wcat, bias, abuf, bbuf, dxbuf);
  scan_local_bf<<<dim3(512), dim3(256), 0, stream>>>(abuf, bbuf, cA, cH);
  scan_carry<<<dim3(32), dim3(256), 0, stream>>>(cA, cH, cIn);
  heads_mfma<<<dim3(512), dim3(256), 0, stream>>>(abuf, bbuf, dxbuf, cIn, wct, bc,
                                                  head_w, hn_g, hn_b, ng, nb, ubuf);
  ffn_mfma<<<dim3(512), dim3(256), 0, stream>>>(ubuf, g_w1t, g_w2t, g_wpt,
                                                b1, b2, bp, out);
}

// Round 3
// 562.513 us; speedup vs baseline: 1.0767x; 1.0767x over previous
//
#include <hip/hip_runtime.h>
#include <hip/hip_bf16.h>
#include <math.h>
#include <stdint.h>

// Problem constants
#define E_DIM 1024
#define D_DIM 64
#define H_DIM 16
#define B_SZ  8
#define L_SEQ 4096
#define M_TOK (B_SZ * L_SEQ)   // 32768 tokens
#define NCAT  2112              // 1024 (a) + 1024 (b) + 64 (dx)
#define NPAD  2304              // 9 tiles of 256: 8 pair-tiles (128 a + 128 b interleaved) + dx tile
#define CHUNK 64                // scan chunk
#define NCHUNK (L_SEQ / CHUNK)  // 64

typedef float  f32x4  __attribute__((ext_vector_type(4)));
typedef __bf16 bf16x8 __attribute__((ext_vector_type(8)));
typedef __bf16 bf16x4 __attribute__((ext_vector_type(4)));

__device__ __forceinline__ float tanh_fast(float v) {
  float vc = fminf(fmaxf(v, -12.f), 12.f);
  float ex = __expf(vc + vc);
  return (ex - 1.f) / (ex + 1.f);
}
__device__ __forceinline__ void load_lds16(const void* g, void* l) {
  __builtin_amdgcn_global_load_lds(
      (const __attribute__((address_space(1))) void*)g,
      (__attribute__((address_space(3))) void*)l, 16, 0, 0);
}

// ---------------------------------------------------------------- cast emb f32 -> bf16
__global__ __launch_bounds__(256) void cast_emb(const float* __restrict__ in,
                                                bf16x4* __restrict__ out) {
  int i = blockIdx.x * 256 + threadIdx.x;      // exactly M_TOK*E/4 threads
  float4 v = ((const float4*)in)[i];
  bf16x4 o;
  o[0] = (__bf16)v.x; o[1] = (__bf16)v.y; o[2] = (__bf16)v.z; o[3] = (__bf16)v.w;
  out[i] = o;
}

// ---------------------------------------------------------------- pack Wa|Wb|Wd -> W^T [NPAD][E] bf16 + bias
// Pair-interleaved: tile nt<8, local col c: pair k = nt*128 + (c>>1);
// even c -> a-gate col k, odd c -> b-gate col k. Tile 8: c<64 -> Wd col c.
__global__ __launch_bounds__(256) void pack_w(
    const float* __restrict__ Wa, const float* __restrict__ ba,
    const float* __restrict__ Wb, const float* __restrict__ bb,
    const float* __restrict__ Wd, const float* __restrict__ bd,
    __bf16* __restrict__ wcat, float* __restrict__ bias) {
  int gid = blockIdx.x * 256 + threadIdx.x;    // exactly NPAD*E threads
  int n = gid >> 10, e = gid & 1023;
  int nt = n >> 8, c = n & 255;
  float w, bv;
  if (nt < 8) {
    int k = nt * 128 + (c >> 1);
    int h = k >> 6, d = k & 63;
    if ((c & 1) == 0) { w = Wa[((h << 10) | e) * 64 + d]; bv = ba[k]; }
    else              { w = Wb[((h << 10) | e) * 64 + d]; bv = bb[k]; }
  } else {
    if (c < 64) { w = Wd[e * 64 + c]; bv = bd[c]; }
    else        { w = 0.f; bv = 0.f; }
  }
  wcat[n * 1024 + e] = (__bf16)w;
  if (e == 0) bias[n] = bv;
}

// ---------------------------------------------------------------- pack FFN weights -> bf16 LDS-image layouts
__global__ __launch_bounds__(256) void pack_ffnw(
    const float* __restrict__ W1, const float* __restrict__ W2,
    const float* __restrict__ Wp,
    __bf16* __restrict__ g_w1t, __bf16* __restrict__ g_w2t,
    __bf16* __restrict__ g_wpt) {
  int idx = blockIdx.x * 256 + threadIdx.x;    // 36864 threads
  if (idx < 16384) {
    int k = idx >> 8, n = idx & 255;
    g_w1t[n * 72 + k] = (__bf16)W1[idx];
  } else if (idx < 32768) {
    int j = idx - 16384; int k = j >> 6, n = j & 63;
    g_w2t[n * 256 + (((k >> 3) ^ (n & 7)) << 3) + (k & 7)] = (__bf16)W2[j];
  } else {
    int j = idx - 32768; int k = j >> 6, n = j & 63;
    g_wpt[n * 72 + k] = (__bf16)Wp[j];
  }
}

// ---------------------------------------------------------------- pack Wc -> WcT[h][e][d] bf16 (B^T layout for MFMA)
__global__ __launch_bounds__(256) void pack_wct(const float* __restrict__ Wc,
                                                __bf16* __restrict__ wct) {
  int idx = blockIdx.x * 256 + threadIdx.x;    // 65536 threads
  int h = idx >> 12, e = (idx >> 6) & 63, d = idx & 63;
  wct[idx] = (__bf16)Wc[h * 4096 + d * 64 + e];
}

// ---------------------------------------------------------------- bf16 MFMA GEMM (256x256, BK=32 dbuf)
// + FUSED chunk-local scan in the epilogue.
// LDS union: staging ring 2 x (A 16KB + B 16KB) = 64 KB  |  scan tile 256 x 272B = 69.6 KB.
// 8 waves: wr = w>>2 (M, 2x128), wc = w&3 (N, 4x64).
// Pair tiles (nt<8): epilogue writes acc -> LDS bf16 (tanh on even cols), then 64-step
// scan per (chunk, pair), coalesced bf16 stores of cumprod/h + f32 chunk carries.
// dx tile (nt==8): direct f32 store of cols 0..63.
__global__ __launch_bounds__(512) void gemm_scan_fused(
    const __bf16* __restrict__ A, const __bf16* __restrict__ Wt,
    const float* __restrict__ bias,
    __bf16* __restrict__ abuf, __bf16* __restrict__ bbuf, float* __restrict__ dxbuf,
    float* __restrict__ cA, float* __restrict__ cH) {
  __shared__ __bf16 lds[34816];               // 69632 B
  // bijective XCD swizzle: 1152 blocks = 8 * 144
  const int id = blockIdx.x;
  const int wg = (id & 7) * 144 + (id >> 3);
  const int mt = wg / 9, nt = wg % 9;
  const int m0 = mt * 256, n0 = nt * 256;
  const int t = threadIdx.x;
  const int w = t >> 6, l = t & 63;
  const int wr = w >> 2, wc = w & 3;
  const int q = l >> 4, c16 = l & 15;
  const int cp = q ^ ((c16 >> 1) & 3);        // swizzled k-chunk position for frag reads

  f32x4 acc[8][4];
#pragma unroll
  for (int i = 0; i < 8; ++i)
#pragma unroll
    for (int j = 0; j < 4; ++j) acc[i][j] = (f32x4)(0.f);

  // stage K-tile kt into slot kt&1: A [256][32] + B [256][32], 4 loads/thread.
  // LDS dest linear (wave-uniform base + lane*16); k-chunk pre-swizzled at the source.
  auto stage = [&](int kt) {
    const int s = kt & 1;
#pragma unroll
    for (int i = 0; i < 2; ++i) {
      int li = i * 512 + t;                   // 16B-chunk id 0..1023
      int rr = li >> 2;                       // tile row 0..255
      int lc = (li & 3) ^ ((rr >> 1) & 3);    // logical k-chunk (swizzle)
      load_lds16(A + (size_t)(m0 + rr) * 1024 + kt * 32 + lc * 8,
                 (char*)lds + s * 32768 + li * 16);
      load_lds16(Wt + (size_t)(n0 + rr) * 1024 + kt * 32 + lc * 8,
                 (char*)lds + s * 32768 + 16384 + li * 16);
    }
  };

  stage(0); stage(1);
#pragma unroll 2
  for (int tt = 0; tt < 32; ++tt) {
    if (tt < 31) { asm volatile("s_waitcnt vmcnt(4)" ::: "memory"); }
    else         { asm volatile("s_waitcnt vmcnt(0)" ::: "memory"); }
    __builtin_amdgcn_s_barrier();
    __builtin_amdgcn_sched_barrier(0);
    const __bf16* Abase = lds + (tt & 1) * 16384;   // elements (32 KB slots)
    const __bf16* Bbase = Abase + 8192;
    bf16x8 bfr[4];
#pragma unroll
    for (int j = 0; j < 4; ++j)
      bfr[j] = *(const bf16x8*)(Bbase + (wc * 64 + j * 16 + c16) * 32 + cp * 8);
#pragma unroll
    for (int i = 0; i < 8; ++i) {
      bf16x8 af = *(const bf16x8*)(Abase + (wr * 128 + i * 16 + c16) * 32 + cp * 8);
#pragma unroll
      for (int j = 0; j < 4; ++j)
        acc[i][j] = __builtin_amdgcn_mfma_f32_16x16x32_bf16(af, bfr[j], acc[i][j], 0, 0, 0);
    }
    __builtin_amdgcn_sched_barrier(0);
    __builtin_amdgcn_s_barrier();
    __builtin_amdgcn_sched_barrier(0);
    if (tt < 30) stage(tt + 2);
  }

  // ---- fused epilogue ----
  const int cbase = m0 >> 6;                  // global chunk base (4 chunks per block)
  if (nt < 8) {
    float bv4[4];
#pragma unroll
    for (int j = 0; j < 4; ++j) bv4[j] = bias[n0 + wc * 64 + j * 16 + c16];
#pragma unroll 1
    for (int ph = 0; ph < 2; ++ph) {
      __syncthreads();                        // prior LDS use complete
      if ((wc >> 1) == ph) {                  // this wave's cols are local 0..127 of this half
#pragma unroll
        for (int j = 0; j < 4; ++j) {
          int cl = (wc & 1) * 64 + j * 16 + c16;
#pragma unroll
          for (int i = 0; i < 8; ++i) {
            int rowb = wr * 128 + i * 16 + q * 4;
#pragma unroll
            for (int r = 0; r < 4; ++r) {
              float v = acc[i][j][r] + bv4[j];
              float val = (c16 & 1) ? v : tanh_fast(v);   // even packed col = a-gate
              *(__bf16*)((char*)lds + (rowb + r) * 272 + cl * 2) = (__bf16)val;
            }
          }
        }
      }
      __syncthreads();
      if (t < 256) {                          // 4 chunks x 64 pairs
        const int c4 = t >> 6, pp = t & 63;
        const int gk = nt * 128 + ph * 64 + pp;
        const int rb = c4 * 64;
        float p = 1.f, h = 0.f;
        size_t g = (size_t)(m0 + rb) * 1024 + gk;
        const char* lrow = (const char*)lds + rb * 272 + pp * 4;
#pragma unroll 4
        for (int st = 0; st < 64; ++st) {
          float a = (float)*(const __bf16*)(lrow);
          float b = (float)*(const __bf16*)(lrow + 2);
          lrow += 272;
          p *= a;
          h = fmaf(a, h, b);
          abuf[g] = (__bf16)p;
          bbuf[g] = (__bf16)h;
          g += 1024;
        }
        int ci = (cbase + c4) * 1024 + gk;
        cA[ci] = p; cH[ci] = h;
      }
    }
  } else {
    if (wc == 0) {                            // dx cols 0..63
      float bv4[4];
#pragma unroll
      for (int j = 0; j < 4; ++j) bv4[j] = bias[n0 + j * 16 + c16];
#pragma unroll
      for (int j = 0; j < 4; ++j) {
        int e = j * 16 + c16;
#pragma unroll
        for (int i = 0; i < 8; ++i) {
          int rowb = m0 + wr * 128 + i * 16 + q * 4;
#pragma unroll
          for (int r = 0; r < 4; ++r)
            dxbuf[(size_t)(rowb + r) * 64 + e] = acc[i][j][r] + bv4[j];
        }
      }
    }
  }
}

// ---------------------------------------------------------------- scan phase 2: carries over chunks (f32)
__global__ __launch_bounds__(256) void scan_carry(
    const float* __restrict__ cA, const float* __restrict__ cH, float* __restrict__ cIn) {
  int gid = blockIdx.x * 256 + threadIdx.x;    // 8192 threads: (b, n)
  int n = gid & 1023, b = gid >> 10;
  float carry = 0.f;
  for (int c = 0; c < NCHUNK; ++c) {
    int idx = (b * NCHUNK + c) * 1024 + n;
    cIn[idx] = carry;                           // exclusive carry into chunk c
    carry = fmaf(cA[idx], carry, cH[idx]);
  }
}

// ---------------------------------------------------------------- heads via MFMA
// 64 tokens/block (= exactly one scan chunk), 4 waves x 16 tokens each; all 16 heads per wave.
__global__ __launch_bounds__(256) void heads_mfma(
    const __bf16* __restrict__ ahat, const __bf16* __restrict__ hloc,
    const float* __restrict__ dxbuf, const float* __restrict__ cIn,
    const __bf16* __restrict__ wct, const float* __restrict__ bch,
    const float* __restrict__ head_w, const float* __restrict__ hng,
    const float* __restrict__ hnb, const float* __restrict__ ng,
    const float* __restrict__ nbv, float* __restrict__ ubuf) {
  __shared__ float carryS[1024];
  const int tid = threadIdx.x, w = tid >> 6, l = tid & 63;
  const int q = l >> 4, c16 = l & 15;
  const int m0 = blockIdx.x * 64;
  const int b = m0 >> 12, c = (m0 & 4095) >> 6;  // chunk of 64 tokens
  const int cb = (b * NCHUNK + c) * 1024;
  ((float4*)carryS)[tid] = ((const float4*)(cIn + cb))[tid];
  __syncthreads();

  const size_t arow = (size_t)(m0 + w * 16 + c16) * 1024;  // A-frag token row

  // dx regs in C layout: token q*4+r, e = j*16+c16
  float dxr[4][4];
#pragma unroll
  for (int j = 0; j < 4; ++j)
#pragma unroll
    for (int r = 0; r < 4; ++r)
      dxr[j][r] = dxbuf[(m0 + w * 16 + q * 4 + r) * 64 + j * 16 + c16];

  f32x4 accum[4];
#pragma unroll
  for (int j = 0; j < 4; ++j) accum[j] = (f32x4)(0.f);

  for (int h = 0; h < H_DIM; ++h) {
    // A fragments: reconstruct h_t = cumprod*carry + local (f32), cast bf16
    bf16x8 af[2];
#pragma unroll
    for (int ks = 0; ks < 2; ++ks) {
      int dbase = h * 64 + ks * 32 + q * 8;
      bf16x8 av = *(const bf16x8*)(ahat + arow + dbase);
      bf16x8 hv = *(const bf16x8*)(hloc + arow + dbase);
      float4 cv0 = *(const float4*)(carryS + dbase);
      float4 cv1 = *(const float4*)(carryS + dbase + 4);
      bf16x8 hf;
      hf[0] = (__bf16)fmaf((float)av[0], cv0.x, (float)hv[0]);
      hf[1] = (__bf16)fmaf((float)av[1], cv0.y, (float)hv[1]);
      hf[2] = (__bf16)fmaf((float)av[2], cv0.z, (float)hv[2]);
      hf[3] = (__bf16)fmaf((float)av[3], cv0.w, (float)hv[3]);
      hf[4] = (__bf16)fmaf((float)av[4], cv1.x, (float)hv[4]);
      hf[5] = (__bf16)fmaf((float)av[5], cv1.y, (float)hv[5]);
      hf[6] = (__bf16)fmaf((float)av[6], cv1.z, (float)hv[6]);
      hf[7] = (__bf16)fmaf((float)av[7], cv1.w, (float)hv[7]);
      af[ks] = hf;
    }
    // GEMM: [16 tokens x 64d] @ WcT[h] -> [16 x 64e]
    f32x4 acc[4];
#pragma unroll
    for (int j = 0; j < 4; ++j) acc[j] = (f32x4)(0.f);
#pragma unroll
    for (int ks = 0; ks < 2; ++ks)
#pragma unroll
      for (int j = 0; j < 4; ++j) {
        bf16x8 bf = *(const bf16x8*)(wct + h * 4096 + (j * 16 + c16) * 64 + ks * 32 + q * 8);
        acc[j] = __builtin_amdgcn_mfma_f32_16x16x32_bf16(af[ks], bf, acc[j], 0, 0, 0);
      }
    // bias + dx, per-head LN over e, weighted accumulate
    float hw = head_w[h];
    float g4[4], be4[4], bb4[4];
#pragma unroll
    for (int j = 0; j < 4; ++j) {
      int nh = h * 64 + j * 16 + c16;
      g4[j] = hng[nh]; bb4[j] = hnb[nh]; be4[j] = bch[nh];
    }
#pragma unroll
    for (int r = 0; r < 4; ++r) {
      float v0 = acc[0][r] + be4[0] + dxr[0][r];
      float v1 = acc[1][r] + be4[1] + dxr[1][r];
      float v2 = acc[2][r] + be4[2] + dxr[2][r];
      float v3 = acc[3][r] + be4[3] + dxr[3][r];
      float s  = (v0 + v1) + (v2 + v3);
      float s2 = fmaf(v0, v0, fmaf(v1, v1, fmaf(v2, v2, v3 * v3)));
#pragma unroll
      for (int off = 1; off < 16; off <<= 1) {
        s  += __shfl_xor(s, off, 64);
        s2 += __shfl_xor(s2, off, 64);
      }
      float mean = s * (1.f / 64.f);
      float var  = fmaf(s2, 1.f / 64.f, -mean * mean);
      float inv  = rsqrtf(fmaxf(var, 0.f) + 1e-5f);
      accum[0][r] = fmaf(hw, fmaf((v0 - mean) * inv, g4[0], bb4[0]), accum[0][r]);
      accum[1][r] = fmaf(hw, fmaf((v1 - mean) * inv, g4[1], bb4[1]), accum[1][r]);
      accum[2][r] = fmaf(hw, fmaf((v2 - mean) * inv, g4[2], bb4[2]), accum[2][r]);
      accum[3][r] = fmaf(hw, fmaf((v3 - mean) * inv, g4[3], bb4[3]), accum[3][r]);
    }
  }
  // z = (dx + accum)/16; u = z + LN(z)
  float ng4[4], nb4[4];
#pragma unroll
  for (int j = 0; j < 4; ++j) { ng4[j] = ng[j * 16 + c16]; nb4[j] = nbv[j * 16 + c16]; }
#pragma unroll
  for (int r = 0; r < 4; ++r) {
    float z0 = (dxr[0][r] + accum[0][r]) * (1.f / 16.f);
    float z1 = (dxr[1][r] + accum[1][r]) * (1.f / 16.f);
    float z2 = (dxr[2][r] + accum[2][r]) * (1.f / 16.f);
    float z3 = (dxr[3][r] + accum[3][r]) * (1.f / 16.f);
    float s  = (z0 + z1) + (z2 + z3);
    float s2 = fmaf(z0, z0, fmaf(z1, z1, fmaf(z2, z2, z3 * z3)));
#pragma unroll
    for (int off = 1; off < 16; off <<= 1) {
      s  += __shfl_xor(s, off, 64);
      s2 += __shfl_xor(s2, off, 64);
    }
    float mean = s * (1.f / 64.f);
    float var  = fmaf(s2, 1.f / 64.f, -mean * mean);
    float inv  = rsqrtf(fmaxf(var, 0.f) + 1e-5f);
    int mrow = (m0 + w * 16 + q * 4 + r) * 64;
    ubuf[mrow + 0 * 16 + c16] = z0 + fmaf((z0 - mean) * inv, ng4[0], nb4[0]);
    ubuf[mrow + 1 * 16 + c16] = z1 + fmaf((z1 - mean) * inv, ng4[1], nb4[1]);
    ubuf[mrow + 2 * 16 + c16] = z2 + fmaf((z2 - mean) * inv, ng4[2], nb4[2]);
    ubuf[mrow + 3 * 16 + c16] = z3 + fmaf((z3 - mean) * inv, ng4[3], nb4[3]);
  }
}

// ---------------------------------------------------------------- FFN via MFMA: 64-token tile, fused 3 GEMMs
__global__ __launch_bounds__(256) void ffn_mfma(
    const float* __restrict__ ubuf,
    const __bf16* __restrict__ g_w1t, const __bf16* __restrict__ g_w2t,
    const __bf16* __restrict__ g_wpt,
    const float* __restrict__ b1, const float* __restrict__ b2,
    const float* __restrict__ bp, float* __restrict__ out) {
  __shared__ __bf16 pool[32768];               // 65536 B
  const int tid = threadIdx.x, w = tid >> 6, l = tid & 63;
  const int q = l >> 4, c16 = l & 15;
  const int m0 = blockIdx.x * 64;
  __bf16* Us  = pool;            // stride 72
  __bf16* W1T = pool + 4608;     // stride 72
  __bf16* T1S = pool;            // stride 256, chunk-swizzled
  __bf16* W2T = pool + 16384;    // stride 256, chunk-swizzled
  __bf16* HoS = pool;            // stride 72
  __bf16* WpT = pool + 4608;     // stride 72

#pragma unroll
  for (int r = 0; r < 16; ++r) {
    int idx = r * 256 + tid, m = idx >> 6, e = idx & 63;
    Us[m * 72 + e] = (__bf16)ubuf[(size_t)(m0 + m) * 64 + e];
  }
#pragma unroll
  for (int r = 0; r < 9; ++r)    // 2304 16B chunks = 36864 B
    load_lds16(g_w1t + (size_t)(r * 256 + tid) * 8,
               (char*)pool + 9216 + (r * 256 + w * 64) * 16);
  __syncthreads();

  f32x4 acc1[16];
#pragma unroll
  for (int j = 0; j < 16; ++j) acc1[j] = (f32x4)(0.f);
#pragma unroll
  for (int ks = 0; ks < 2; ++ks) {
    bf16x8 a = *(const bf16x8*)(Us + (w * 16 + c16) * 72 + ks * 32 + q * 8);
#pragma unroll
    for (int j = 0; j < 16; ++j) {
      bf16x8 b = *(const bf16x8*)(W1T + (j * 16 + c16) * 72 + ks * 32 + q * 8);
      acc1[j] = __builtin_amdgcn_mfma_f32_16x16x32_bf16(a, b, acc1[j], 0, 0, 0);
    }
  }
  __syncthreads();

#pragma unroll
  for (int r = 0; r < 8; ++r)    // 2048 chunks = 32768 B
    load_lds16(g_w2t + (size_t)(r * 256 + tid) * 8,
               (char*)pool + 32768 + (r * 256 + w * 64) * 16);
#pragma unroll
  for (int j = 0; j < 16; ++j) {
    int n = j * 16 + c16;
    float bv = b1[n];
#pragma unroll
    for (int rr = 0; rr < 4; ++rr) {
      int m = w * 16 + q * 4 + rr;
      float x = acc1[j][rr] + bv;
      float g = 0.5f * x * (1.f + erff(x * 0.70710678118654752f));
      T1S[m * 256 + (((n >> 3) ^ (m & 7)) << 3) + (n & 7)] = (__bf16)g;
    }
  }
  __syncthreads();

  f32x4 acc2[4];
#pragma unroll
  for (int j = 0; j < 4; ++j) acc2[j] = (f32x4)(0.f);
  const int arow2 = w * 16 + c16;
#pragma unroll
  for (int ks = 0; ks < 8; ++ks) {
    bf16x8 a = *(const bf16x8*)(T1S + arow2 * 256 + (((ks * 4 + q) ^ (arow2 & 7)) << 3));
#pragma unroll
    for (int j = 0; j < 4; ++j) {
      int brow = j * 16 + c16;
      bf16x8 b = *(const bf16x8*)(W2T + brow * 256 + (((ks * 4 + q) ^ (brow & 7)) << 3));
      acc2[j] = __builtin_amdgcn_mfma_f32_16x16x32_bf16(a, b, acc2[j], 0, 0, 0);
    }
  }
  __syncthreads();

#pragma unroll
  for (int r = 0; r < 2; ++r)    // 512 of 576 chunks
    load_lds16(g_wpt + (size_t)(r * 256 + tid) * 8,
               (char*)pool + 9216 + (r * 256 + w * 64) * 16);
  if (tid < 64)                  // last 64 chunks, wave 0
    load_lds16(g_wpt + (size_t)(512 + tid) * 8, (char*)pool + 9216 + 512 * 16);
#pragma unroll
  for (int j = 0; j < 4; ++j) {
    int e = j * 16 + c16;
    float bv = b2[e];
#pragma unroll
    for (int rr = 0; rr < 4; ++rr) {
      int m = w * 16 + q * 4 + rr;
      float hres = acc2[j][rr] + bv + ubuf[(size_t)(m0 + m) * 64 + e];
      HoS[m * 72 + e] = (__bf16)hres;
    }
  }
  __syncthreads();

  f32x4 acc3[4];
#pragma unroll
  for (int j = 0; j < 4; ++j) acc3[j] = (f32x4)(0.f);
#pragma unroll
  for (int ks = 0; ks < 2; ++ks) {
    bf16x8 a = *(const bf16x8*)(HoS + (w * 16 + c16) * 72 + ks * 32 + q * 8);
#pragma unroll
    for (int j = 0; j < 4; ++j) {
      bf16x8 b = *(const bf16x8*)(WpT + (j * 16 + c16) * 72 + ks * 32 + q * 8);
      acc3[j] = __builtin_amdgcn_mfma_f32_16x16x32_bf16(a, b, acc3[j], 0, 0, 0);
    }
  }
#pragma unroll
  for (int j = 0; j < 4; ++j) {
    int e = j * 16 + c16;
    float bv = bp[e];
#pragma unroll
    for (int rr = 0; rr < 4; ++rr) {
      int m = w * 16 + q * 4 + rr;
      out[(size_t)(m0 + m) * 64 + e] = acc3[j][rr] + bv;
    }
  }
}

// ----------------------------------------------------------------
extern "C" void kernel_launch(void* const* d_in, const int* in_sizes, int n_in,
                              void* d_out, int out_size, void* d_ws, size_t ws_size,
                              hipStream_t stream) {
  const float* emb    = (const float*)d_in[0];
  const float* Wa     = (const float*)d_in[1];
  const float* ba     = (const float*)d_in[2];
  const float* Wb     = (const float*)d_in[3];
  const float* bb     = (const float*)d_in[4];
  const float* Wc     = (const float*)d_in[5];
  const float* bc     = (const float*)d_in[6];
  const float* head_w = (const float*)d_in[7];
  const float* hn_g   = (const float*)d_in[8];
  const float* hn_b   = (const float*)d_in[9];
  const float* Wd     = (const float*)d_in[10];
  const float* bd     = (const float*)d_in[11];
  const float* W1     = (const float*)d_in[12];
  const float* b1     = (const float*)d_in[13];
  const float* W2     = (const float*)d_in[14];
  const float* b2     = (const float*)d_in[15];
  const float* Wp     = (const float*)d_in[16];
  const float* bp     = (const float*)d_in[17];
  const float* ng     = (const float*)d_in[18];
  const float* nb     = (const float*)d_in[19];
  float* out = (float*)d_out;

  char* wsp = (char*)d_ws;
  size_t off = 0;
  auto alloc = [&](size_t bytes) -> char* {
    char* p = wsp + off;
    off += (bytes + 255) & ~(size_t)255;
    return p;
  };
  __bf16* embh  = (__bf16*)alloc((size_t)M_TOK * E_DIM * 2);   //  67 MB
  __bf16* wcat  = (__bf16*)alloc((size_t)NPAD * E_DIM * 2);    // 4.7 MB
  float*  bias  = (float*)alloc((size_t)NPAD * 4);
  __bf16* abuf  = (__bf16*)alloc((size_t)M_TOK * 1024 * 2);    // 67 MB (cumprod)
  __bf16* bbuf  = (__bf16*)alloc((size_t)M_TOK * 1024 * 2);    // 67 MB (local h)
  float*  dxbuf = (float*)alloc((size_t)M_TOK * 64 * 4);       // 8.4 MB
  float*  cA    = (float*)alloc((size_t)512 * 1024 * 4);
  float*  cH    = (float*)alloc((size_t)512 * 1024 * 4);
  float*  cIn   = (float*)alloc((size_t)512 * 1024 * 4);
  float*  ubuf  = (float*)alloc((size_t)M_TOK * 64 * 4);       // 8.4 MB
  __bf16* g_w1t = (__bf16*)alloc((size_t)256 * 72 * 2);
  __bf16* g_w2t = (__bf16*)alloc((size_t)64 * 256 * 2);
  __bf16* g_wpt = (__bf16*)alloc((size_t)64 * 72 * 2);
  __bf16* wct   = (__bf16*)alloc((size_t)H_DIM * 64 * 64 * 2); // 128 KB

  cast_emb<<<dim3(32768), dim3(256), 0, stream>>>(emb, (bf16x4*)embh);
  pack_w<<<dim3(9216), dim3(256), 0, stream>>>(Wa, ba, Wb, bb, Wd, bd, wcat, bias);
  pack_ffnw<<<dim3(144), dim3(256), 0, stream>>>(W1, W2, Wp, g_w1t, g_w2t, g_wpt);
  pack_wct<<<dim3(256), dim3(256), 0, stream>>>(Wc, wct);
  gemm_scan_fused<<<dim3(1152), dim3(512), 0, stream>>>(embh, wcat, bias, abuf, bbuf,
                                                        dxbuf, cA, cH);
  scan_carry<<<dim3(32), dim3(256), 0, stream>>>(cA, cH, cIn);
  heads_mfma<<<dim3(512), dim3(256), 0, stream>>>(abuf, bbuf, dxbuf, cIn, wct, bc,
                                                  head_w, hn_g, hn_b, ng, nb, ubuf);
  ffn_mfma<<<dim3(512), dim3(256), 0, stream>>>(ubuf, g_w1t, g_w2t, g_wpt,
                                                b1, b2, bp, out);
}

// Round 4
// 551.684 us; speedup vs baseline: 1.0978x; 1.0196x over previous
//
#include <hip/hip_runtime.h>
#include <hip/hip_bf16.h>
#include <math.h>
#include <stdint.h>

// Problem constants
#define E_DIM 1024
#define D_DIM 64
#define H_DIM 16
#define B_SZ  8
#define L_SEQ 4096
#define M_TOK (B_SZ * L_SEQ)   // 32768 tokens
#define NCAT  2112              // 1024 (a) + 1024 (b) + 64 (dx)
#define NPAD  2304              // 9 tiles of 256: 8 pair-tiles (128 a + 128 b interleaved) + dx tile
#define CHUNK 64                // scan chunk
#define NCHUNK (L_SEQ / CHUNK)  // 64

typedef float  f32x4  __attribute__((ext_vector_type(4)));
typedef __bf16 bf16x8 __attribute__((ext_vector_type(8)));
typedef __bf16 bf16x4 __attribute__((ext_vector_type(4)));

__device__ __forceinline__ float tanh_fast(float v) {
  float vc = fminf(fmaxf(v, -12.f), 12.f);
  float ex = __expf(vc + vc);
  return (ex - 1.f) / (ex + 1.f);
}
__device__ __forceinline__ void load_lds16(const void* g, void* l) {
  __builtin_amdgcn_global_load_lds(
      (const __attribute__((address_space(1))) void*)g,
      (__attribute__((address_space(3))) void*)l, 16, 0, 0);
}

// ---------------------------------------------------------------- cast emb f32 -> bf16
__global__ __launch_bounds__(256) void cast_emb(const float* __restrict__ in,
                                                bf16x4* __restrict__ out) {
  int i = blockIdx.x * 256 + threadIdx.x;      // exactly M_TOK*E/4 threads
  float4 v = ((const float4*)in)[i];
  bf16x4 o;
  o[0] = (__bf16)v.x; o[1] = (__bf16)v.y; o[2] = (__bf16)v.z; o[3] = (__bf16)v.w;
  out[i] = o;
}

// ---------------------------------------------------------------- merged packing kernel
// Region 0: Wa|Wb|Wd -> W^T [NPAD][E] bf16 + bias (pair-interleaved a/b tiles).
// Region 1: FFN weights -> bf16 LDS-image layouts.
// Region 2: Wc -> WcT[h][e][d] bf16.
#define PK0 (NPAD * 1024)        // 2359296
#define PK1 36864
#define PK2 65536
__global__ __launch_bounds__(256) void pack_all(
    const float* __restrict__ Wa, const float* __restrict__ ba,
    const float* __restrict__ Wb, const float* __restrict__ bb,
    const float* __restrict__ Wd, const float* __restrict__ bd,
    const float* __restrict__ W1, const float* __restrict__ W2,
    const float* __restrict__ Wp, const float* __restrict__ Wc,
    __bf16* __restrict__ wcat, float* __restrict__ bias,
    __bf16* __restrict__ g_w1t, __bf16* __restrict__ g_w2t,
    __bf16* __restrict__ g_wpt, __bf16* __restrict__ wct) {
  int gid = blockIdx.x * 256 + threadIdx.x;    // PK0+PK1+PK2 = 2461696 threads
  if (gid < PK0) {
    int n = gid >> 10, e = gid & 1023;
    int nt = n >> 8, c = n & 255;
    float w, bv;
    if (nt < 8) {
      int k = nt * 128 + (c >> 1);
      int h = k >> 6, d = k & 63;
      if ((c & 1) == 0) { w = Wa[((h << 10) | e) * 64 + d]; bv = ba[k]; }
      else              { w = Wb[((h << 10) | e) * 64 + d]; bv = bb[k]; }
    } else {
      if (c < 64) { w = Wd[e * 64 + c]; bv = bd[c]; }
      else        { w = 0.f; bv = 0.f; }
    }
    wcat[n * 1024 + e] = (__bf16)w;
    if (e == 0) bias[n] = bv;
  } else if (gid < PK0 + PK1) {
    int idx = gid - PK0;
    if (idx < 16384) {
      int k = idx >> 8, n = idx & 255;
      g_w1t[n * 72 + k] = (__bf16)W1[idx];
    } else if (idx < 32768) {
      int j = idx - 16384; int k = j >> 6, n = j & 63;
      g_w2t[n * 256 + (((k >> 3) ^ (n & 7)) << 3) + (k & 7)] = (__bf16)W2[j];
    } else {
      int j = idx - 32768; int k = j >> 6, n = j & 63;
      g_wpt[n * 72 + k] = (__bf16)Wp[j];
    }
  } else {
    int idx = gid - PK0 - PK1;
    int h = idx >> 12, e = (idx >> 6) & 63, d = idx & 63;
    wct[idx] = (__bf16)Wc[h * 4096 + d * 64 + e];
  }
}

// ---------------------------------------------------------------- bf16 MFMA GEMM (256x256, BK=32 dbuf)
// + FUSED chunk-local scan in the epilogue.  (unchanged from prior round — control)
__global__ __launch_bounds__(512) void gemm_scan_fused(
    const __bf16* __restrict__ A, const __bf16* __restrict__ Wt,
    const float* __restrict__ bias,
    __bf16* __restrict__ abuf, __bf16* __restrict__ bbuf, float* __restrict__ dxbuf,
    float* __restrict__ cA, float* __restrict__ cH) {
  __shared__ __bf16 lds[34816];               // 69632 B
  // bijective XCD swizzle: 1152 blocks = 8 * 144
  const int id = blockIdx.x;
  const int wg = (id & 7) * 144 + (id >> 3);
  const int mt = wg / 9, nt = wg % 9;
  const int m0 = mt * 256, n0 = nt * 256;
  const int t = threadIdx.x;
  const int w = t >> 6, l = t & 63;
  const int wr = w >> 2, wc = w & 3;
  const int q = l >> 4, c16 = l & 15;
  const int cp = q ^ ((c16 >> 1) & 3);        // swizzled k-chunk position for frag reads

  f32x4 acc[8][4];
#pragma unroll
  for (int i = 0; i < 8; ++i)
#pragma unroll
    for (int j = 0; j < 4; ++j) acc[i][j] = (f32x4)(0.f);

  auto stage = [&](int kt) {
    const int s = kt & 1;
#pragma unroll
    for (int i = 0; i < 2; ++i) {
      int li = i * 512 + t;                   // 16B-chunk id 0..1023
      int rr = li >> 2;                       // tile row 0..255
      int lc = (li & 3) ^ ((rr >> 1) & 3);    // logical k-chunk (swizzle)
      load_lds16(A + (size_t)(m0 + rr) * 1024 + kt * 32 + lc * 8,
                 (char*)lds + s * 32768 + li * 16);
      load_lds16(Wt + (size_t)(n0 + rr) * 1024 + kt * 32 + lc * 8,
                 (char*)lds + s * 32768 + 16384 + li * 16);
    }
  };

  stage(0); stage(1);
#pragma unroll 2
  for (int tt = 0; tt < 32; ++tt) {
    if (tt < 31) { asm volatile("s_waitcnt vmcnt(4)" ::: "memory"); }
    else         { asm volatile("s_waitcnt vmcnt(0)" ::: "memory"); }
    __builtin_amdgcn_s_barrier();
    __builtin_amdgcn_sched_barrier(0);
    const __bf16* Abase = lds + (tt & 1) * 16384;   // elements (32 KB slots)
    const __bf16* Bbase = Abase + 8192;
    bf16x8 bfr[4];
#pragma unroll
    for (int j = 0; j < 4; ++j)
      bfr[j] = *(const bf16x8*)(Bbase + (wc * 64 + j * 16 + c16) * 32 + cp * 8);
#pragma unroll
    for (int i = 0; i < 8; ++i) {
      bf16x8 af = *(const bf16x8*)(Abase + (wr * 128 + i * 16 + c16) * 32 + cp * 8);
#pragma unroll
      for (int j = 0; j < 4; ++j)
        acc[i][j] = __builtin_amdgcn_mfma_f32_16x16x32_bf16(af, bfr[j], acc[i][j], 0, 0, 0);
    }
    __builtin_amdgcn_sched_barrier(0);
    __builtin_amdgcn_s_barrier();
    __builtin_amdgcn_sched_barrier(0);
    if (tt < 30) stage(tt + 2);
  }

  // ---- fused epilogue ----
  const int cbase = m0 >> 6;                  // global chunk base (4 chunks per block)
  if (nt < 8) {
    float bv4[4];
#pragma unroll
    for (int j = 0; j < 4; ++j) bv4[j] = bias[n0 + wc * 64 + j * 16 + c16];
#pragma unroll 1
    for (int ph = 0; ph < 2; ++ph) {
      __syncthreads();                        // prior LDS use complete
      if ((wc >> 1) == ph) {                  // this wave's cols are local 0..127 of this half
#pragma unroll
        for (int j = 0; j < 4; ++j) {
          int cl = (wc & 1) * 64 + j * 16 + c16;
#pragma unroll
          for (int i = 0; i < 8; ++i) {
            int rowb = wr * 128 + i * 16 + q * 4;
#pragma unroll
            for (int r = 0; r < 4; ++r) {
              float v = acc[i][j][r] + bv4[j];
              float val = (c16 & 1) ? v : tanh_fast(v);   // even packed col = a-gate
              *(__bf16*)((char*)lds + (rowb + r) * 272 + cl * 2) = (__bf16)val;
            }
          }
        }
      }
      __syncthreads();
      if (t < 256) {                          // 4 chunks x 64 pairs
        const int c4 = t >> 6, pp = t & 63;
        const int gk = nt * 128 + ph * 64 + pp;
        const int rb = c4 * 64;
        float p = 1.f, h = 0.f;
        size_t g = (size_t)(m0 + rb) * 1024 + gk;
        const char* lrow = (const char*)lds + rb * 272 + pp * 4;
#pragma unroll 4
        for (int st = 0; st < 64; ++st) {
          float a = (float)*(const __bf16*)(lrow);
          float b = (float)*(const __bf16*)(lrow + 2);
          lrow += 272;
          p *= a;
          h = fmaf(a, h, b);
          abuf[g] = (__bf16)p;
          bbuf[g] = (__bf16)h;
          g += 1024;
        }
        int ci = (cbase + c4) * 1024 + gk;
        cA[ci] = p; cH[ci] = h;
      }
    }
  } else {
    if (wc == 0) {                            // dx cols 0..63
      float bv4[4];
#pragma unroll
      for (int j = 0; j < 4; ++j) bv4[j] = bias[n0 + j * 16 + c16];
#pragma unroll
      for (int j = 0; j < 4; ++j) {
        int e = j * 16 + c16;
#pragma unroll
        for (int i = 0; i < 8; ++i) {
          int rowb = m0 + wr * 128 + i * 16 + q * 4;
#pragma unroll
          for (int r = 0; r < 4; ++r)
            dxbuf[(size_t)(rowb + r) * 64 + e] = acc[i][j][r] + bv4[j];
        }
      }
    }
  }
}

// ---------------------------------------------------------------- scan phase 2: carries over chunks (f32)
// 8-deep batched loads to hide the dependent-chain latency (32 blocks only).
__global__ __launch_bounds__(256) void scan_carry(
    const float* __restrict__ cA, const float* __restrict__ cH, float* __restrict__ cIn) {
  int gid = blockIdx.x * 256 + threadIdx.x;    // 8192 threads: (b, n)
  int n = gid & 1023, b = gid >> 10;
  const int base = b * NCHUNK * 1024 + n;
  float carry = 0.f;
#pragma unroll 1
  for (int c0 = 0; c0 < NCHUNK; c0 += 8) {
    float a8[8], h8[8];
#pragma unroll
    for (int i = 0; i < 8; ++i) {
      int idx = base + (c0 + i) * 1024;
      a8[i] = cA[idx]; h8[i] = cH[idx];
    }
#pragma unroll
    for (int i = 0; i < 8; ++i) {
      cIn[base + (c0 + i) * 1024] = carry;     // exclusive carry into chunk c0+i
      carry = fmaf(a8[i], carry, h8[i]);
    }
  }
}

// ---------------------------------------------------------------- FUSED heads + FFN
// 64 tokens/block (= one scan chunk), 4 waves x 16 tokens; all 16 heads per wave.
// heads: out = h@Wc + bc + dx -> per-head LN -> weighted sum -> z -> u (in regs, C-layout)
// ffn:   u -> GELU MLP -> +u -> @Wp + bp, u staged to LDS directly from regs.
__global__ __launch_bounds__(256) void heads_ffn(
    const __bf16* __restrict__ ahat, const __bf16* __restrict__ hloc,
    const float* __restrict__ dxbuf, const float* __restrict__ cIn,
    const __bf16* __restrict__ wct, const float* __restrict__ bch,
    const float* __restrict__ head_w, const float* __restrict__ hng,
    const float* __restrict__ hnb, const float* __restrict__ ng,
    const float* __restrict__ nbv,
    const __bf16* __restrict__ g_w1t, const __bf16* __restrict__ g_w2t,
    const __bf16* __restrict__ g_wpt,
    const float* __restrict__ b1, const float* __restrict__ b2,
    const float* __restrict__ bp, float* __restrict__ out) {
  __shared__ __bf16 pool[32768];               // 64 KB; bytes [0,4096) double as carryS
  float* carryS = (float*)pool;
  const int tid = threadIdx.x, w = tid >> 6, l = tid & 63;
  const int q = l >> 4, c16 = l & 15;
  const int m0 = blockIdx.x * 64;
  __bf16* Us  = pool;            // stride 72, bytes [0,9216)
  __bf16* W1T = pool + 4608;     // stride 72, bytes [9216,46080)
  __bf16* T1S = pool;            // stride 256 swizzled, bytes [0,32768)
  __bf16* W2T = pool + 16384;    // stride 256 swizzled, bytes [32768,65536)
  __bf16* HoS = pool;            // stride 72
  __bf16* WpT = pool + 4608;     // stride 72

  // prefetch W1T early (lands during heads phase; consumed after a __syncthreads)
#pragma unroll
  for (int r = 0; r < 9; ++r)    // 2304 16B chunks = 36864 B
    load_lds16(g_w1t + (size_t)(r * 256 + tid) * 8,
               (char*)pool + 9216 + (r * 256 + w * 64) * 16);

  const int b = m0 >> 12, c = (m0 & 4095) >> 6;  // chunk of 64 tokens
  const int cb = (b * NCHUNK + c) * 1024;
  ((float4*)carryS)[tid] = ((const float4*)(cIn + cb))[tid];
  __syncthreads();

  const size_t arow = (size_t)(m0 + w * 16 + c16) * 1024;  // A-frag token row

  // dx regs in C layout: token q*4+r, e = j*16+c16
  float dxr[4][4];
#pragma unroll
  for (int j = 0; j < 4; ++j)
#pragma unroll
    for (int r = 0; r < 4; ++r)
      dxr[j][r] = dxbuf[(m0 + w * 16 + q * 4 + r) * 64 + j * 16 + c16];

  f32x4 accum[4];
#pragma unroll
  for (int j = 0; j < 4; ++j) accum[j] = (f32x4)(0.f);

  for (int h = 0; h < H_DIM; ++h) {
    bf16x8 af[2];
#pragma unroll
    for (int ks = 0; ks < 2; ++ks) {
      int dbase = h * 64 + ks * 32 + q * 8;
      bf16x8 av = *(const bf16x8*)(ahat + arow + dbase);
      bf16x8 hv = *(const bf16x8*)(hloc + arow + dbase);
      float4 cv0 = *(const float4*)(carryS + dbase);
      float4 cv1 = *(const float4*)(carryS + dbase + 4);
      bf16x8 hf;
      hf[0] = (__bf16)fmaf((float)av[0], cv0.x, (float)hv[0]);
      hf[1] = (__bf16)fmaf((float)av[1], cv0.y, (float)hv[1]);
      hf[2] = (__bf16)fmaf((float)av[2], cv0.z, (float)hv[2]);
      hf[3] = (__bf16)fmaf((float)av[3], cv0.w, (float)hv[3]);
      hf[4] = (__bf16)fmaf((float)av[4], cv1.x, (float)hv[4]);
      hf[5] = (__bf16)fmaf((float)av[5], cv1.y, (float)hv[5]);
      hf[6] = (__bf16)fmaf((float)av[6], cv1.z, (float)hv[6]);
      hf[7] = (__bf16)fmaf((float)av[7], cv1.w, (float)hv[7]);
      af[ks] = hf;
    }
    f32x4 acc[4];
#pragma unroll
    for (int j = 0; j < 4; ++j) acc[j] = (f32x4)(0.f);
#pragma unroll
    for (int ks = 0; ks < 2; ++ks)
#pragma unroll
      for (int j = 0; j < 4; ++j) {
        bf16x8 bf = *(const bf16x8*)(wct + h * 4096 + (j * 16 + c16) * 64 + ks * 32 + q * 8);
        acc[j] = __builtin_amdgcn_mfma_f32_16x16x32_bf16(af[ks], bf, acc[j], 0, 0, 0);
      }
    float hw = head_w[h];
    float g4[4], be4[4], bb4[4];
#pragma unroll
    for (int j = 0; j < 4; ++j) {
      int nh = h * 64 + j * 16 + c16;
      g4[j] = hng[nh]; bb4[j] = hnb[nh]; be4[j] = bch[nh];
    }
#pragma unroll
    for (int r = 0; r < 4; ++r) {
      float v0 = acc[0][r] + be4[0] + dxr[0][r];
      float v1 = acc[1][r] + be4[1] + dxr[1][r];
      float v2 = acc[2][r] + be4[2] + dxr[2][r];
      float v3 = acc[3][r] + be4[3] + dxr[3][r];
      float s  = (v0 + v1) + (v2 + v3);
      float s2 = fmaf(v0, v0, fmaf(v1, v1, fmaf(v2, v2, v3 * v3)));
#pragma unroll
      for (int off = 1; off < 16; off <<= 1) {
        s  += __shfl_xor(s, off, 64);
        s2 += __shfl_xor(s2, off, 64);
      }
      float mean = s * (1.f / 64.f);
      float var  = fmaf(s2, 1.f / 64.f, -mean * mean);
      float inv  = rsqrtf(fmaxf(var, 0.f) + 1e-5f);
      accum[0][r] = fmaf(hw, fmaf((v0 - mean) * inv, g4[0], bb4[0]), accum[0][r]);
      accum[1][r] = fmaf(hw, fmaf((v1 - mean) * inv, g4[1], bb4[1]), accum[1][r]);
      accum[2][r] = fmaf(hw, fmaf((v2 - mean) * inv, g4[2], bb4[2]), accum[2][r]);
      accum[3][r] = fmaf(hw, fmaf((v3 - mean) * inv, g4[3], bb4[3]), accum[3][r]);
    }
  }
  // z = (dx + accum)/16; u = z + LN(z)  (kept in regs, C layout)
  float u4[4][4];
  float ng4[4], nb4[4];
#pragma unroll
  for (int j = 0; j < 4; ++j) { ng4[j] = ng[j * 16 + c16]; nb4[j] = nbv[j * 16 + c16]; }
#pragma unroll
  for (int r = 0; r < 4; ++r) {
    float z0 = (dxr[0][r] + accum[0][r]) * (1.f / 16.f);
    float z1 = (dxr[1][r] + accum[1][r]) * (1.f / 16.f);
    float z2 = (dxr[2][r] + accum[2][r]) * (1.f / 16.f);
    float z3 = (dxr[3][r] + accum[3][r]) * (1.f / 16.f);
    float s  = (z0 + z1) + (z2 + z3);
    float s2 = fmaf(z0, z0, fmaf(z1, z1, fmaf(z2, z2, z3 * z3)));
#pragma unroll
    for (int off = 1; off < 16; off <<= 1) {
      s  += __shfl_xor(s, off, 64);
      s2 += __shfl_xor(s2, off, 64);
    }
    float mean = s * (1.f / 64.f);
    float var  = fmaf(s2, 1.f / 64.f, -mean * mean);
    float inv  = rsqrtf(fmaxf(var, 0.f) + 1e-5f);
    u4[0][r] = z0 + fmaf((z0 - mean) * inv, ng4[0], nb4[0]);
    u4[1][r] = z1 + fmaf((z1 - mean) * inv, ng4[1], nb4[1]);
    u4[2][r] = z2 + fmaf((z2 - mean) * inv, ng4[2], nb4[2]);
    u4[3][r] = z3 + fmaf((z3 - mean) * inv, ng4[3], nb4[3]);
  }
  __syncthreads();               // all carryS reads done before Us overwrite
#pragma unroll
  for (int j = 0; j < 4; ++j)
#pragma unroll
    for (int r = 0; r < 4; ++r)
      Us[(w * 16 + q * 4 + r) * 72 + j * 16 + c16] = (__bf16)u4[j][r];
  __syncthreads();               // Us + W1T (vmcnt drained) ready

  // ---- FFN GEMM 1: [64x64] @ W1 -> [64x256] ----
  f32x4 acc1[16];
#pragma unroll
  for (int j = 0; j < 16; ++j) acc1[j] = (f32x4)(0.f);
#pragma unroll
  for (int ks = 0; ks < 2; ++ks) {
    bf16x8 a = *(const bf16x8*)(Us + (w * 16 + c16) * 72 + ks * 32 + q * 8);
#pragma unroll
    for (int j = 0; j < 16; ++j) {
      bf16x8 bfr = *(const bf16x8*)(W1T + (j * 16 + c16) * 72 + ks * 32 + q * 8);
      acc1[j] = __builtin_amdgcn_mfma_f32_16x16x32_bf16(a, bfr, acc1[j], 0, 0, 0);
    }
  }
  __syncthreads();

#pragma unroll
  for (int r = 0; r < 8; ++r)    // stage W2T: 2048 chunks = 32768 B
    load_lds16(g_w2t + (size_t)(r * 256 + tid) * 8,
               (char*)pool + 32768 + (r * 256 + w * 64) * 16);
#pragma unroll
  for (int j = 0; j < 16; ++j) {
    int n = j * 16 + c16;
    float bv = b1[n];
#pragma unroll
    for (int rr = 0; rr < 4; ++rr) {
      int m = w * 16 + q * 4 + rr;
      float x = acc1[j][rr] + bv;
      float g = 0.5f * x * (1.f + erff(x * 0.70710678118654752f));
      T1S[m * 256 + (((n >> 3) ^ (m & 7)) << 3) + (n & 7)] = (__bf16)g;
    }
  }
  __syncthreads();

  // ---- FFN GEMM 2: [64x256] @ W2 -> [64x64] ----
  f32x4 acc2[4];
#pragma unroll
  for (int j = 0; j < 4; ++j) acc2[j] = (f32x4)(0.f);
  const int arow2 = w * 16 + c16;
#pragma unroll
  for (int ks = 0; ks < 8; ++ks) {
    bf16x8 a = *(const bf16x8*)(T1S + arow2 * 256 + (((ks * 4 + q) ^ (arow2 & 7)) << 3));
#pragma unroll
    for (int j = 0; j < 4; ++j) {
      int brow = j * 16 + c16;
      bf16x8 bfr = *(const bf16x8*)(W2T + brow * 256 + (((ks * 4 + q) ^ (brow & 7)) << 3));
      acc2[j] = __builtin_amdgcn_mfma_f32_16x16x32_bf16(a, bfr, acc2[j], 0, 0, 0);
    }
  }
  __syncthreads();

#pragma unroll
  for (int r = 0; r < 2; ++r)    // stage WpT: 512 of 576 chunks
    load_lds16(g_wpt + (size_t)(r * 256 + tid) * 8,
               (char*)pool + 9216 + (r * 256 + w * 64) * 16);
  if (tid < 64)                  // last 64 chunks, wave 0
    load_lds16(g_wpt + (size_t)(512 + tid) * 8, (char*)pool + 9216 + 512 * 16);
#pragma unroll
  for (int j = 0; j < 4; ++j) {
    int e = j * 16 + c16;
    float bv = b2[e];
#pragma unroll
    for (int rr = 0; rr < 4; ++rr) {
      int m = w * 16 + q * 4 + rr;
      float hres = acc2[j][rr] + bv + u4[j][rr];   // residual from regs
      HoS[m * 72 + e] = (__bf16)hres;
    }
  }
  __syncthreads();

  // ---- FFN GEMM 3: [64x64] @ Wp -> out ----
  f32x4 acc3[4];
#pragma unroll
  for (int j = 0; j < 4; ++j) acc3[j] = (f32x4)(0.f);
#pragma unroll
  for (int ks = 0; ks < 2; ++ks) {
    bf16x8 a = *(const bf16x8*)(HoS + (w * 16 + c16) * 72 + ks * 32 + q * 8);
#pragma unroll
    for (int j = 0; j < 4; ++j) {
      bf16x8 bfr = *(const bf16x8*)(WpT + (j * 16 + c16) * 72 + ks * 32 + q * 8);
      acc3[j] = __builtin_amdgcn_mfma_f32_16x16x32_bf16(a, bfr, acc3[j], 0, 0, 0);
    }
  }
#pragma unroll
  for (int j = 0; j < 4; ++j) {
    int e = j * 16 + c16;
    float bv = bp[e];
#pragma unroll
    for (int rr = 0; rr < 4; ++rr) {
      int m = w * 16 + q * 4 + rr;
      out[(size_t)(m0 + m) * 64 + e] = acc3[j][rr] + bv;
    }
  }
}

// ----------------------------------------------------------------
extern "C" void kernel_launch(void* const* d_in, const int* in_sizes, int n_in,
                              void* d_out, int out_size, void* d_ws, size_t ws_size,
                              hipStream_t stream) {
  const float* emb    = (const float*)d_in[0];
  const float* Wa     = (const float*)d_in[1];
  const float* ba     = (const float*)d_in[2];
  const float* Wb     = (const float*)d_in[3];
  const float* bb     = (const float*)d_in[4];
  const float* Wc     = (const float*)d_in[5];
  const float* bc     = (const float*)d_in[6];
  const float* head_w = (const float*)d_in[7];
  const float* hn_g   = (const float*)d_in[8];
  const float* hn_b   = (const float*)d_in[9];
  const float* Wd     = (const float*)d_in[10];
  const float* bd     = (const float*)d_in[11];
  const float* W1     = (const float*)d_in[12];
  const float* b1     = (const float*)d_in[13];
  const float* W2     = (const float*)d_in[14];
  const float* b2     = (const float*)d_in[15];
  const float* Wp     = (const float*)d_in[16];
  const float* bp     = (const float*)d_in[17];
  const float* ng     = (const float*)d_in[18];
  const float* nb     = (const float*)d_in[19];
  float* out = (float*)d_out;

  char* wsp = (char*)d_ws;
  size_t off = 0;
  auto alloc = [&](size_t bytes) -> char* {
    char* p = wsp + off;
    off += (bytes + 255) & ~(size_t)255;
    return p;
  };
  __bf16* embh  = (__bf16*)alloc((size_t)M_TOK * E_DIM * 2);   //  67 MB
  __bf16* wcat  = (__bf16*)alloc((size_t)NPAD * E_DIM * 2);    // 4.7 MB
  float*  bias  = (float*)alloc((size_t)NPAD * 4);
  __bf16* abuf  = (__bf16*)alloc((size_t)M_TOK * 1024 * 2);    // 67 MB (cumprod)
  __bf16* bbuf  = (__bf16*)alloc((size_t)M_TOK * 1024 * 2);    // 67 MB (local h)
  float*  dxbuf = (float*)alloc((size_t)M_TOK * 64 * 4);       // 8.4 MB
  float*  cA    = (float*)alloc((size_t)512 * 1024 * 4);
  float*  cH    = (float*)alloc((size_t)512 * 1024 * 4);
  float*  cIn   = (float*)alloc((size_t)512 * 1024 * 4);
  __bf16* g_w1t = (__bf16*)alloc((size_t)256 * 72 * 2);
  __bf16* g_w2t = (__bf16*)alloc((size_t)64 * 256 * 2);
  __bf16* g_wpt = (__bf16*)alloc((size_t)64 * 72 * 2);
  __bf16* wct   = (__bf16*)alloc((size_t)H_DIM * 64 * 64 * 2); // 128 KB

  cast_emb<<<dim3(32768), dim3(256), 0, stream>>>(emb, (bf16x4*)embh);
  pack_all<<<dim3(9616), dim3(256), 0, stream>>>(Wa, ba, Wb, bb, Wd, bd,
                                                 W1, W2, Wp, Wc,
                                                 wcat, bias, g_w1t, g_w2t, g_wpt, wct);
  gemm_scan_fused<<<dim3(1152), dim3(512), 0, stream>>>(embh, wcat, bias, abuf, bbuf,
                                                        dxbuf, cA, cH);
  scan_carry<<<dim3(32), dim3(256), 0, stream>>>(cA, cH, cIn);
  heads_ffn<<<dim3(512), dim3(256), 0, stream>>>(abuf, bbuf, dxbuf, cIn, wct, bc,
                                                 head_w, hn_g, hn_b, ng, nb,
                                                 g_w1t, g_w2t, g_wpt,
                                                 b1, b2, bp, out);
}